// Round 1
// baseline (281.807 us; speedup 1.0000x reference)
//
#include <hip/hip_runtime.h>
#include <hip/hip_bf16.h>
#include <stdint.h>

typedef __attribute__((ext_vector_type(8))) short bf16x8;
typedef __attribute__((ext_vector_type(4))) float f32x4;

#define BATCH 16
#define CH    256
#define HW    56
#define HWHW  3136   // 56*56
#define NK    8

// ---- workspace layout (bytes) ----
#define XPT_BYTES   30408704ul          // [16][58][64][256] bf16
#define WK_BYTES    18874368ul          // [16][9][256][256] bf16
#define POOL_BYTES  16384ul
#define ALPHA_BYTES 512ul

__device__ __forceinline__ void gl_lds16(const void* g, void* l) {
    __builtin_amdgcn_global_load_lds((const __attribute__((address_space(1))) uint32_t*)g,
                                     (__attribute__((address_space(3))) uint32_t*)l, 16, 0, 0);
}

// ---------------- stage 1: global average pool ----------------
__global__ void pool_kernel(const float* __restrict__ x, float* __restrict__ pooled) {
    int bc = blockIdx.x;                       // b*256 + c
    const float* p = x + (size_t)bc * HWHW;
    float s = 0.f;
    for (int t = threadIdx.x; t < HWHW; t += 256) s += p[t];
    for (int off = 32; off; off >>= 1) s += __shfl_down(s, off);
    __shared__ float ws4[4];
    if ((threadIdx.x & 63) == 0) ws4[threadIdx.x >> 6] = s;
    __syncthreads();
    if (threadIdx.x == 0)
        pooled[bc] = (ws4[0] + ws4[1] + ws4[2] + ws4[3]) * (1.0f / 3136.0f);
}

// ---------------- stage 2: transpose+pad x -> bf16 [b][58][64][256] ----------------
__global__ void xpose_kernel(const float* __restrict__ x, __hip_bfloat16* __restrict__ xp) {
    int ic4 = blockIdx.x;     // channel chunk of 64
    int y   = blockIdx.y;     // data row 0..55  -> padded row y+1
    int b   = blockIdx.z;
    __shared__ __hip_bfloat16 t[64][57];
    int lane = threadIdx.x & 63;
    int quad = threadIdx.x >> 6;              // 0..3
    const float* src = x + ((size_t)(b * CH + ic4 * 64) * HW + y) * HW;
    for (int ii = quad; ii < 64; ii += 4) {
        if (lane < 56) t[ii][lane] = __float2bfloat16(src[(size_t)ii * HWHW + lane]);
    }
    __syncthreads();
    __hip_bfloat16* dst = xp + ((size_t)(b * 58 + (y + 1)) * 64) * 256 + (size_t)ic4 * 64;
    for (int xx = quad; xx < 56; xx += 4) {
        dst[(size_t)(xx + 1) * 256 + lane] = t[lane][xx];
    }
}

// ---------------- stage 3: MLP + softmax -> alphas [16][8] ----------------
__global__ void mlp_kernel(const float* __restrict__ pooled,
                           const float* __restrict__ w1, const float* __restrict__ b1,
                           const float* __restrict__ w2, const float* __restrict__ b2,
                           float* __restrict__ alphas) {
    __shared__ float hs[16][64];
    __shared__ float sc[16][8];
    int t = threadIdx.x;
    for (int idx = t; idx < 16 * 64; idx += 256) {
        int b = idx >> 6, j = idx & 63;
        float acc = b1[j];
        const float* pb = pooled + b * 256;
        for (int c = 0; c < 256; ++c) acc += pb[c] * w1[c * 64 + j];
        hs[b][j] = fmaxf(acc, 0.0f);
    }
    __syncthreads();
    if (t < 128) {
        int b = t >> 3, k = t & 7;
        float acc = b2[k];
        for (int j = 0; j < 64; ++j) acc += hs[b][j] * w2[j * 8 + k];
        sc[b][k] = acc;
    }
    __syncthreads();
    if (t < 16) {
        float m = -1e30f;
        for (int k = 0; k < 8; ++k) m = fmaxf(m, sc[t][k]);
        float s = 0.f, e[8];
        for (int k = 0; k < 8; ++k) { e[k] = expf(sc[t][k] - m); s += e[k]; }
        float inv = 1.0f / s;
        for (int k = 0; k < 8; ++k) alphas[t * 8 + k] = e[k] * inv;
    }
}

// ---------------- stage 4: mix kernels -> wk [b][kk][o][i] bf16 ----------------
__global__ void wmix_kernel(const float* __restrict__ kern, const float* __restrict__ alphas,
                            __hip_bfloat16* __restrict__ wk) {
    __shared__ float al[16][8];
    int t = threadIdx.x;
    if (t < 128) al[t >> 3][t & 7] = alphas[t];
    __syncthreads();
    int idx = blockIdx.x * 256 + t;           // o*256 + i
    float kv[8][9];
    const float* kp = kern + (size_t)idx * 9;
#pragma unroll
    for (int k = 0; k < 8; ++k)
#pragma unroll
        for (int q = 0; q < 9; ++q) kv[k][q] = kp[(size_t)k * 589824 + q];
#pragma unroll 1
    for (int b = 0; b < 16; ++b) {
#pragma unroll
        for (int q = 0; q < 9; ++q) {
            float acc = 0.f;
#pragma unroll
            for (int k = 0; k < 8; ++k) acc += al[b][k] * kv[k][q];
            wk[(((size_t)(b * 9 + q) * 256) << 8) + idx] = __float2bfloat16(acc);
        }
    }
}

// ---------------- stage 5: per-sample conv as MFMA implicit GEMM ----------------
// grid: (mtile 2, ntile 14, b 16), block 256 (4 waves = 2M x 2N)
// BM=128 (8 frags), BN=224 = 4 out-rows x 56 cols (14 frags); K: 8 i-chunks x 9 (kh,kw)
__global__ void __launch_bounds__(256, 2)
conv_kernel(const __hip_bfloat16* __restrict__ xpT, const __hip_bfloat16* __restrict__ wk,
            float* __restrict__ out) {
    __shared__ short lds_x[6 * 64 * 32];   // [r6][c64][i32], slot-swizzled   24KB
    __shared__ short lds_a[128 * 32];      // [o128][i32],  slot-swizzled      8KB

    const int tid   = threadIdx.x;
    const int lane  = tid & 63;
    const int g     = lane >> 4;           // 0..3 -> i-slot / acc row group
    const int l15   = lane & 15;
    const int w     = tid >> 6;            // wave 0..3
    const int wm    = w >> 1;              // 0..1
    const int wn    = w & 1;               // 0..1
    const int w64   = tid & ~63;

    const int mtile = blockIdx.x;          // 0..1
    const int y0    = blockIdx.y * 4;      // out-row base (also padded-row base)
    const int b     = blockIdx.z;

    // per-lane fragment geometry (unrolled-const indexed only)
    int cellb[7], c3[7], rr[7], cc[7];
#pragma unroll
    for (int fn = 0; fn < 7; ++fn) {
        int n = wn * 112 + fn * 16 + l15;  // 0..223
        int r = n / 56, c = n % 56;
        rr[fn] = r; cc[fn] = c;
        cellb[fn] = r * 64 + c;
        c3[fn] = c & 3;
    }
    // A-frag lane byte offset: [o][i32] cells of 64B, slot = g ^ (o&3), o&3 == l15&3
    const int aoff = (wm * 64 + l15) * 64 + ((g ^ (l15 & 3)) << 4);

    f32x4 acc[4][7];
#pragma unroll
    for (int fm = 0; fm < 4; ++fm)
#pragma unroll
        for (int fn = 0; fn < 7; ++fn) acc[fm][fn] = (f32x4){0.f, 0.f, 0.f, 0.f};

    const size_t xb = ((size_t)b * 58 + y0) * 64 * 256;   // elem offset of [b][y0][0][0]

    for (int ci = 0; ci < 8; ++ci) {
        // ---- stage x-tile [6][64][i-chunk 32] via global_load_lds (swizzled source) ----
#pragma unroll
        for (int it = 0; it < 6; ++it) {
            int idx  = it * 256 + tid;          // 16B-chunk id
            int slot = idx & 3, cell = idx >> 2;
            int c = cell & 63, r = cell >> 6;
            int tslot = slot ^ (c & 3);
            const __hip_bfloat16* src = xpT + xb + ((size_t)(r * 64 + c)) * 256 + ci * 32 + tslot * 8;
            gl_lds16(src, (char*)lds_x + (it * 256 + w64) * 16);
        }
        for (int kk = 0; kk < 9; ++kk) {
            const int kh = kk / 3, kw = kk % 3;
            // ---- stage A-tile [128][32] ----
            const size_t wbase = (((size_t)(b * 9 + kk) * 256 + mtile * 128)) << 8;
#pragma unroll
            for (int it = 0; it < 2; ++it) {
                int idx  = it * 256 + tid;
                int slot = idx & 3, o = idx >> 2;
                int tslot = slot ^ (o & 3);
                const __hip_bfloat16* src = wk + wbase + ((size_t)o << 8) + ci * 32 + tslot * 8;
                gl_lds16(src, (char*)lds_a + (it * 256 + w64) * 16);
            }
            __syncthreads();   // drains global_load_lds (vmcnt 0) + aligns waves

            bf16x8 af[4];
#pragma unroll
            for (int fm = 0; fm < 4; ++fm)
                af[fm] = *(const bf16x8*)((const char*)lds_a + aoff + fm * 1024);
#pragma unroll
            for (int fn = 0; fn < 7; ++fn) {
                int cell = cellb[fn] + kh * 64 + kw;
                int slot = g ^ ((c3[fn] + kw) & 3);
                bf16x8 bfv = *(const bf16x8*)((const char*)lds_x + cell * 64 + (slot << 4));
#pragma unroll
                for (int fm = 0; fm < 4; ++fm)
                    acc[fm][fn] = __builtin_amdgcn_mfma_f32_16x16x32_bf16(af[fm], bfv, acc[fm][fn], 0, 0, 0);
            }
            __syncthreads();   // protect lds_a (and lds_x on last kk) before restage
        }
    }

    // ---- epilogue: C/D layout col=l15, row=4*g+reg ----
    const int mbase = mtile * 128 + wm * 64;
#pragma unroll
    for (int fm = 0; fm < 4; ++fm)
#pragma unroll
        for (int fn = 0; fn < 7; ++fn) {
            int o = mbase + fm * 16 + 4 * g;
            float* op = out + (((size_t)b * 256 + o) * 56 + (y0 + rr[fn])) * 56 + cc[fn];
#pragma unroll
            for (int r = 0; r < 4; ++r) op[(size_t)r * HWHW] = acc[fm][fn][r];
        }
}

extern "C" void kernel_launch(void* const* d_in, const int* in_sizes, int n_in,
                              void* d_out, int out_size, void* d_ws, size_t ws_size,
                              hipStream_t stream) {
    const float* x    = (const float*)d_in[0];
    const float* kern = (const float*)d_in[1];
    const float* w1   = (const float*)d_in[2];
    const float* b1   = (const float*)d_in[3];
    const float* w2   = (const float*)d_in[4];
    const float* b2   = (const float*)d_in[5];
    float* out = (float*)d_out;

    char* wsp = (char*)d_ws;
    __hip_bfloat16* xpT    = (__hip_bfloat16*)wsp;
    __hip_bfloat16* wkbuf  = (__hip_bfloat16*)(wsp + XPT_BYTES);
    float*          pooled = (float*)(wsp + XPT_BYTES + WK_BYTES);
    float*          alphas = (float*)(wsp + XPT_BYTES + WK_BYTES + POOL_BYTES);

    hipMemsetAsync(xpT, 0, XPT_BYTES, stream);

    pool_kernel<<<dim3(BATCH * CH), dim3(256), 0, stream>>>(x, pooled);
    xpose_kernel<<<dim3(4, 56, 16), dim3(256), 0, stream>>>(x, xpT);
    mlp_kernel<<<dim3(1), dim3(256), 0, stream>>>(pooled, w1, b1, w2, b2, alphas);
    wmix_kernel<<<dim3(256), dim3(256), 0, stream>>>(kern, alphas, wkbuf);
    conv_kernel<<<dim3(2, 14, 16), dim3(256), 0, stream>>>(xpT, wkbuf, out);
}

// Round 2
// 250.977 us; speedup vs baseline: 1.1228x; 1.1228x over previous
//
#include <hip/hip_runtime.h>
#include <hip/hip_bf16.h>
#include <stdint.h>

typedef __attribute__((ext_vector_type(8))) short bf16x8;
typedef __attribute__((ext_vector_type(4))) float f32x4;

#define BATCH 16
#define CH    256
#define HW    56
#define HWHW  3136   // 56*56
#define NK    8

// ---- workspace layout (bytes) ----
#define XPT_BYTES   30408704ul          // [16][58][64][256] bf16
#define WK_BYTES    18874368ul          // [16][9][256][256] bf16
#define POOL_BYTES  16384ul
#define ALPHA_BYTES 512ul

__device__ __forceinline__ void gl_lds16(const void* g, void* l) {
    __builtin_amdgcn_global_load_lds((const __attribute__((address_space(1))) uint32_t*)g,
                                     (__attribute__((address_space(3))) uint32_t*)l, 16, 0, 0);
}

__device__ __forceinline__ float bf16bits_to_f32(short h) {
    return __uint_as_float(((uint32_t)(uint16_t)h) << 16);
}

// ---------------- stage 1: fused transpose+pad+pool ----------------
// block (ys 0..27, b): data rows y = 2*ys, 2*ys+1 -> padded rows y+1
// out layout xpT[b][row 58][x 64][ch 256] bf16; also pooled[b][c] via atomics.
__global__ void __launch_bounds__(256, 2)
xpose_pool_kernel(const float* __restrict__ x, __hip_bfloat16* __restrict__ xp,
                  float* __restrict__ pooled) {
    __shared__ short tile[2 * 56 * 256];   // [r][x][ch ^ ((x&7)<<3)]  57,344 B
    const int tid = threadIdx.x;
    const int ys  = blockIdx.x;            // 0..27
    const int b   = blockIdx.y;
    const int y0  = ys * 2;

    // ---- load: 28 iters of float4 (coalesced 448B runs per channel) ----
    const float* xb = x + (size_t)b * CH * HWHW + (size_t)y0 * HW;
    for (int it = 0; it < 28; ++it) {
        int idx = it * 256 + tid;          // 0..7167
        int ch  = idx / 28;
        int xi  = idx - ch * 28;
        int r   = xi / 14;
        int x4  = (xi - r * 14) * 4;
        const float4 v = *(const float4*)(xb + (size_t)ch * HWHW + r * HW + x4);
        const float* vf = (const float*)&v;
#pragma unroll
        for (int j = 0; j < 4; ++j) {
            __hip_bfloat16 h = __float2bfloat16(vf[j]);
            tile[(r * 56 + x4 + j) * 256 + (ch ^ (((x4 & 7) | j) << 3))] = *(const short*)&h;
        }
    }
    __syncthreads();

    // ---- pool partials from bf16 tile (thread = channel) ----
    {
        float s = 0.f;
        const int ch = tid;
        for (int r = 0; r < 2; ++r)
            for (int xx = 0; xx < 56; ++xx)
                s += bf16bits_to_f32(tile[(r * 56 + xx) * 256 + (ch ^ ((xx & 7) << 3))]);
        atomicAdd(&pooled[b * 256 + ch], s * (1.0f / 3136.0f));
    }

    // ---- write out: 14 iters of 16B stores, fully coalesced ----
    __hip_bfloat16* dst0 = xp + ((size_t)(b * 58 + y0 + 1) * 64 + 1) * 256;
    for (int it = 0; it < 14; ++it) {
        int idx = it * 256 + tid;          // 0..3583
        int ch0 = (idx & 31) * 8;
        int pos = idx >> 5;                // 0..111
        int r = pos / 56, xx = pos - (pos / 56) * 56;
        bf16x8 vv = *(const bf16x8*)&tile[(r * 56 + xx) * 256 + (ch0 ^ ((xx & 7) << 3))];
        *(bf16x8*)(dst0 + ((size_t)(r * 64 + xx)) * 256 + ch0) = vv;
    }

    // ---- halo zeroing (replaces 30MB memset) ----
    bf16x8 z = {};
    if (tid < 128) {                       // cols x=0, x=57 for this block's 2 rows
        int r   = tid >> 6;
        int c2  = (tid >> 5) & 1;
        int ch0 = (tid & 31) * 8;
        *(bf16x8*)(xp + ((size_t)(b * 58 + y0 + 1 + r) * 64 + (c2 ? 57 : 0)) * 256 + ch0) = z;
    }
    if (ys == 0 || ys == 27) {             // full padded rows 0 and 57
        int p = (ys == 0) ? 0 : 57;
        __hip_bfloat16* rowp = xp + (size_t)(b * 58 + p) * 64 * 256;
        for (int it = tid; it < 2048; it += 256)
            *(bf16x8*)(rowp + (size_t)it * 8) = z;
    }
}

// ---------------- stage 2: MLP + softmax -> alphas [16][8] ----------------
__global__ void mlp_kernel(const float* __restrict__ pooled,
                           const float* __restrict__ w1, const float* __restrict__ b1,
                           const float* __restrict__ w2, const float* __restrict__ b2,
                           float* __restrict__ alphas) {
    __shared__ float hs[16][64];
    __shared__ float sc[16][8];
    int t = threadIdx.x;
    for (int idx = t; idx < 16 * 64; idx += 256) {
        int b = idx >> 6, j = idx & 63;
        float acc = b1[j];
        const float* pb = pooled + b * 256;
        for (int c = 0; c < 256; ++c) acc += pb[c] * w1[c * 64 + j];
        hs[b][j] = fmaxf(acc, 0.0f);
    }
    __syncthreads();
    if (t < 128) {
        int b = t >> 3, k = t & 7;
        float acc = b2[k];
        for (int j = 0; j < 64; ++j) acc += hs[b][j] * w2[j * 8 + k];
        sc[b][k] = acc;
    }
    __syncthreads();
    if (t < 16) {
        float m = -1e30f;
        for (int k = 0; k < 8; ++k) m = fmaxf(m, sc[t][k]);
        float s = 0.f, e[8];
        for (int k = 0; k < 8; ++k) { e[k] = expf(sc[t][k] - m); s += e[k]; }
        float inv = 1.0f / s;
        for (int k = 0; k < 8; ++k) alphas[t * 8 + k] = e[k] * inv;
    }
}

// ---------------- stage 3: mix kernels -> wk [b][kk][o][i] bf16 ----------------
__global__ void wmix_kernel(const float* __restrict__ kern, const float* __restrict__ alphas,
                            __hip_bfloat16* __restrict__ wk) {
    __shared__ float al[16][8];
    int t = threadIdx.x;
    if (t < 128) al[t >> 3][t & 7] = alphas[t];
    __syncthreads();
    int idx = blockIdx.x * 256 + t;           // o*256 + i
    float kv[8][9];
    const float* kp = kern + (size_t)idx * 9;
#pragma unroll
    for (int k = 0; k < 8; ++k)
#pragma unroll
        for (int q = 0; q < 9; ++q) kv[k][q] = kp[(size_t)k * 589824 + q];
#pragma unroll 1
    for (int b = 0; b < 16; ++b) {
#pragma unroll
        for (int q = 0; q < 9; ++q) {
            float acc = 0.f;
#pragma unroll
            for (int k = 0; k < 8; ++k) acc += al[b][k] * kv[k][q];
            wk[(((size_t)(b * 9 + q) * 256) << 8) + idx] = __float2bfloat16(acc);
        }
    }
}

// ---------------- stage 4: per-sample conv, 2-phase pipelined MFMA GEMM ----------------
// flat grid 448 (XCD-chunked swizzle), block 256 (4 waves = 2M x 2N)
// BM=128, BN=224 = 4 out-rows x 56; K: 72 steps = 8 i-chunks x 9 (kh,kw)
__global__ void __launch_bounds__(256, 2)
conv_kernel(const __hip_bfloat16* __restrict__ xpT, const __hip_bfloat16* __restrict__ wk,
            float* __restrict__ out) {
    __shared__ short lds_x[2][6 * 64 * 32];   // 2 x 24KB, slot-swizzled
    __shared__ short lds_a[2][128 * 32];      // 2 x 8KB,  slot-swizzled

    const int tid   = threadIdx.x;
    const int lane  = tid & 63;
    const int g     = lane >> 4;
    const int l15   = lane & 15;
    const int w     = tid >> 6;
    const int wm    = w >> 1;
    const int wn    = w & 1;
    const int w64   = tid & ~63;

    // XCD-chunked bijective swizzle: 448 blocks -> 56 consecutive per XCD (2 batches)
    const int flat  = blockIdx.x;
    const int swzid = (flat & 7) * 56 + (flat >> 3);
    const int b     = swzid / 28;
    const int rem   = swzid - b * 28;
    const int mtile = rem & 1;
    const int y0    = (rem >> 1) * 4;

    int cellb[7], c3[7], rr[7], cc[7];
#pragma unroll
    for (int fn = 0; fn < 7; ++fn) {
        int n = wn * 112 + fn * 16 + l15;
        int r = n / 56, c = n % 56;
        rr[fn] = r; cc[fn] = c;
        cellb[fn] = r * 64 + c;
        c3[fn] = c & 3;
    }
    const int aoff = (wm * 64 + l15) * 64 + ((g ^ (l15 & 3)) << 4);

    f32x4 acc[4][7];
#pragma unroll
    for (int fm = 0; fm < 4; ++fm)
#pragma unroll
        for (int fn = 0; fn < 7; ++fn) acc[fm][fn] = (f32x4){0.f, 0.f, 0.f, 0.f};

    const size_t xb = ((size_t)b * 58 + y0) * 64 * 256;

#define STAGE_X(CI, BUF)                                                            \
    do {                                                                            \
        _Pragma("unroll")                                                           \
        for (int it = 0; it < 6; ++it) {                                            \
            int idx = it * 256 + tid;                                               \
            int slot = idx & 3, cell = idx >> 2;                                    \
            int c = cell & 63;                                                      \
            int tslot = slot ^ (c & 3);                                             \
            const __hip_bfloat16* src = xpT + xb + (size_t)cell * 256 + (CI) * 32 + tslot * 8; \
            gl_lds16(src, (char*)lds_x[BUF] + (it * 256 + w64) * 16);               \
        }                                                                           \
    } while (0)

#define STAGE_A(CI, KK, BUF)                                                        \
    do {                                                                            \
        const size_t wbase = ((size_t)((b * 9 + (KK)) * 256 + mtile * 128)) << 8;   \
        _Pragma("unroll")                                                           \
        for (int it = 0; it < 2; ++it) {                                            \
            int idx = it * 256 + tid;                                               \
            int slot = idx & 3, o = idx >> 2;                                       \
            int tslot = slot ^ (o & 3);                                             \
            const __hip_bfloat16* src = wk + wbase + ((size_t)o << 8) + (CI) * 32 + tslot * 8; \
            gl_lds16(src, (char*)lds_a[BUF] + (it * 256 + w64) * 16);               \
        }                                                                           \
    } while (0)

    // prologue
    STAGE_X(0, 0);
    STAGE_A(0, 0, 0);
    __syncthreads();

    int cab = 0, cxb = 0;
    int kk = 0, kh = 0, kw = 0, ci = 0;
#pragma unroll 1
    for (int s = 0; s < 72; ++s) {
        int nkk = kk + 1, nci = ci;
        if (nkk == 9) { nkk = 0; ++nci; }
        if (s < 71) {                      // prefetch next step's tiles
            STAGE_A(nci, nkk, cab ^ 1);
            if (kk == 8) STAGE_X(nci, cxb ^ 1);
        }

        bf16x8 af[4];
#pragma unroll
        for (int fm = 0; fm < 4; ++fm)
            af[fm] = *(const bf16x8*)((const char*)lds_a[cab] + aoff + fm * 1024);
#pragma unroll
        for (int fn = 0; fn < 7; ++fn) {
            int cell = cellb[fn] + kh * 64 + kw;
            int slot = g ^ ((c3[fn] + kw) & 3);
            bf16x8 bfv = *(const bf16x8*)((const char*)lds_x[cxb] + cell * 64 + (slot << 4));
#pragma unroll
            for (int fm = 0; fm < 4; ++fm)
                acc[fm][fn] = __builtin_amdgcn_mfma_f32_16x16x32_bf16(af[fm], bfv, acc[fm][fn], 0, 0, 0);
        }

        __syncthreads();                   // single barrier: drains staging, flips buffers
        cab ^= 1;
        if (kk == 8) cxb ^= 1;
        kk = nkk; ci = nci;
        if (++kw == 3) { kw = 0; if (++kh == 3) kh = 0; }
    }

    // epilogue: C/D layout col=l15, row=4*g+reg
    const int mbase = mtile * 128 + wm * 64;
#pragma unroll
    for (int fm = 0; fm < 4; ++fm)
#pragma unroll
        for (int fn = 0; fn < 7; ++fn) {
            int o = mbase + fm * 16 + 4 * g;
            float* op = out + (((size_t)b * 256 + o) * 56 + (y0 + rr[fn])) * 56 + cc[fn];
#pragma unroll
            for (int r = 0; r < 4; ++r) op[(size_t)r * HWHW] = acc[fm][fn][r];
        }
#undef STAGE_X
#undef STAGE_A
}

extern "C" void kernel_launch(void* const* d_in, const int* in_sizes, int n_in,
                              void* d_out, int out_size, void* d_ws, size_t ws_size,
                              hipStream_t stream) {
    const float* x    = (const float*)d_in[0];
    const float* kern = (const float*)d_in[1];
    const float* w1   = (const float*)d_in[2];
    const float* b1   = (const float*)d_in[3];
    const float* w2   = (const float*)d_in[4];
    const float* b2   = (const float*)d_in[5];
    float* out = (float*)d_out;

    char* wsp = (char*)d_ws;
    __hip_bfloat16* xpT    = (__hip_bfloat16*)wsp;
    __hip_bfloat16* wkbuf  = (__hip_bfloat16*)(wsp + XPT_BYTES);
    float*          pooled = (float*)(wsp + XPT_BYTES + WK_BYTES);
    float*          alphas = (float*)(wsp + XPT_BYTES + WK_BYTES + POOL_BYTES);

    hipMemsetAsync(pooled, 0, POOL_BYTES, stream);

    xpose_pool_kernel<<<dim3(28, 16), dim3(256), 0, stream>>>(x, xpT, pooled);
    mlp_kernel<<<dim3(1), dim3(256), 0, stream>>>(pooled, w1, b1, w2, b2, alphas);
    wmix_kernel<<<dim3(256), dim3(256), 0, stream>>>(kern, alphas, wkbuf);
    conv_kernel<<<dim3(448), dim3(256), 0, stream>>>(xpT, wkbuf, out);
}

// Round 3
// 244.056 us; speedup vs baseline: 1.1547x; 1.0284x over previous
//
#include <hip/hip_runtime.h>
#include <hip/hip_bf16.h>
#include <stdint.h>

typedef __attribute__((ext_vector_type(8))) short bf16x8;
typedef __attribute__((ext_vector_type(4))) float f32x4;

#define BATCH 16
#define CH    256
#define HW    56
#define HWHW  3136   // 56*56
#define NK    8

// ---- workspace layout (bytes) ----
#define XPT_BYTES   30408704ul          // [16][58][64][256] bf16
#define WK_BYTES    18874368ul          // fragment-major: [b*9+kk][ci 8][frag 16][l15 16][g 4][e 8] bf16
#define POOL_BYTES  16384ul
#define ALPHA_BYTES 512ul

__device__ __forceinline__ void gl_lds16(const void* g, void* l) {
    __builtin_amdgcn_global_load_lds((const __attribute__((address_space(1))) uint32_t*)g,
                                     (__attribute__((address_space(3))) uint32_t*)l, 16, 0, 0);
}

__device__ __forceinline__ float bf16bits_to_f32(short h) {
    return __uint_as_float(((uint32_t)(uint16_t)h) << 16);
}

// ---------------- stage 1: fused transpose+pad+pool ----------------
__global__ void __launch_bounds__(256, 2)
xpose_pool_kernel(const float* __restrict__ x, __hip_bfloat16* __restrict__ xp,
                  float* __restrict__ pooled) {
    __shared__ short tile[2 * 56 * 256];   // [r][x][ch ^ ((x&7)<<3)]
    const int tid = threadIdx.x;
    const int ys  = blockIdx.x;            // 0..27
    const int b   = blockIdx.y;
    const int y0  = ys * 2;

    const float* xb = x + (size_t)b * CH * HWHW + (size_t)y0 * HW;
    for (int it = 0; it < 28; ++it) {
        int idx = it * 256 + tid;
        int ch  = idx / 28;
        int xi  = idx - ch * 28;
        int r   = xi / 14;
        int x4  = (xi - r * 14) * 4;
        const float4 v = *(const float4*)(xb + (size_t)ch * HWHW + r * HW + x4);
        const float* vf = (const float*)&v;
#pragma unroll
        for (int j = 0; j < 4; ++j) {
            __hip_bfloat16 h = __float2bfloat16(vf[j]);
            tile[(r * 56 + x4 + j) * 256 + (ch ^ (((x4 & 7) | j) << 3))] = *(const short*)&h;
        }
    }
    __syncthreads();

    {
        float s = 0.f;
        const int ch = tid;
        for (int r = 0; r < 2; ++r)
            for (int xx = 0; xx < 56; ++xx)
                s += bf16bits_to_f32(tile[(r * 56 + xx) * 256 + (ch ^ ((xx & 7) << 3))]);
        atomicAdd(&pooled[b * 256 + ch], s * (1.0f / 3136.0f));
    }

    __hip_bfloat16* dst0 = xp + ((size_t)(b * 58 + y0 + 1) * 64 + 1) * 256;
    for (int it = 0; it < 14; ++it) {
        int idx = it * 256 + tid;
        int ch0 = (idx & 31) * 8;
        int pos = idx >> 5;
        int r = pos / 56, xx = pos - (pos / 56) * 56;
        bf16x8 vv = *(const bf16x8*)&tile[(r * 56 + xx) * 256 + (ch0 ^ ((xx & 7) << 3))];
        *(bf16x8*)(dst0 + ((size_t)(r * 64 + xx)) * 256 + ch0) = vv;
    }

    bf16x8 z = {};
    if (tid < 128) {
        int r   = tid >> 6;
        int c2  = (tid >> 5) & 1;
        int ch0 = (tid & 31) * 8;
        *(bf16x8*)(xp + ((size_t)(b * 58 + y0 + 1 + r) * 64 + (c2 ? 57 : 0)) * 256 + ch0) = z;
    }
    if (ys == 0 || ys == 27) {
        int p = (ys == 0) ? 0 : 57;
        __hip_bfloat16* rowp = xp + (size_t)(b * 58 + p) * 64 * 256;
        for (int it = tid; it < 2048; it += 256)
            *(bf16x8*)(rowp + (size_t)it * 8) = z;
    }
}

// ---------------- stage 2: MLP + softmax, one block per batch sample ----------------
__global__ void __launch_bounds__(256)
mlp_kernel(const float* __restrict__ pooled,
           const float* __restrict__ w1, const float* __restrict__ b1,
           const float* __restrict__ w2, const float* __restrict__ b2,
           float* __restrict__ alphas) {
    const int b = blockIdx.x;
    __shared__ float pl[256];
    __shared__ float hp[4][64];
    __shared__ float h[64];
    __shared__ float sc[8];
    int t = threadIdx.x;
    pl[t] = pooled[b * 256 + t];
    __syncthreads();
    int j = t & 63, part = t >> 6;
    float s = 0.f;
    const float* w1p = w1 + part * 64 * 64 + j;       // lanes j consecutive -> coalesced
#pragma unroll 8
    for (int c = 0; c < 64; ++c) s += pl[part * 64 + c] * w1p[c * 64];
    hp[part][j] = s;
    __syncthreads();
    if (t < 64) h[t] = fmaxf(hp[0][t] + hp[1][t] + hp[2][t] + hp[3][t] + b1[t], 0.f);
    __syncthreads();
    if (t < 8) {
        float acc = b2[t];
#pragma unroll 8
        for (int jj = 0; jj < 64; ++jj) acc += h[jj] * w2[jj * 8 + t];
        sc[t] = acc;
    }
    __syncthreads();
    if (t == 0) {
        float m = sc[0];
#pragma unroll
        for (int k = 1; k < 8; ++k) m = fmaxf(m, sc[k]);
        float ssum = 0.f, e[8];
#pragma unroll
        for (int k = 0; k < 8; ++k) { e[k] = expf(sc[k] - m); ssum += e[k]; }
        float inv = 1.0f / ssum;
#pragma unroll
        for (int k = 0; k < 8; ++k) alphas[b * 8 + k] = e[k] * inv;
    }
}

// ---------------- stage 3: mix kernels -> fragment-major wk ----------------
// wk byte addr for (b,q,o,i):
//   (b*9+q)*131072 + (i>>5)*16384 + (o>>4)*1024 + (o&15)*64 + ((i>>3)&3)*16 + (i&7)*2
__global__ void wmix_kernel(const float* __restrict__ kern, const float* __restrict__ alphas,
                            __hip_bfloat16* __restrict__ wk) {
    __shared__ float al[16][8];
    int t = threadIdx.x;
    if (t < 128) al[t >> 3][t & 7] = alphas[t];
    __syncthreads();
    const int o = blockIdx.x, i = t;
    const int idx = o * 256 + i;
    const size_t ibase = (size_t)((i >> 5) * 16384 + ((o >> 4)) * 1024 + (o & 15) * 64 +
                                  ((i >> 3) & 3) * 16 + (i & 7) * 2);
    float kv[8][9];
    const float* kp = kern + (size_t)idx * 9;
#pragma unroll
    for (int k = 0; k < 8; ++k)
#pragma unroll
        for (int q = 0; q < 9; ++q) kv[k][q] = kp[(size_t)k * 589824 + q];
    char* wkb = (char*)wk;
#pragma unroll 1
    for (int b = 0; b < 16; ++b) {
#pragma unroll
        for (int q = 0; q < 9; ++q) {
            float acc = 0.f;
#pragma unroll
            for (int k = 0; k < 8; ++k) acc += al[b][k] * kv[k][q];
            __hip_bfloat16 h = __float2bfloat16(acc);
            *(short*)(wkb + (size_t)(b * 9 + q) * 131072 + ibase) = *(const short*)&h;
        }
    }
}

// ---------------- stage 4: conv — A in registers, X in LDS, 8 barriers total ----------------
// flat grid 448 (XCD-chunked swizzle), block 256 (4 waves = 2M x 2N)
// BM=128, BN=224 = 4 out-rows x 56; K: 8 chunks of 32 ch x 9 taps, chunk body fully unrolled
__global__ void __launch_bounds__(256, 2)
conv_kernel(const __hip_bfloat16* __restrict__ xpT, const __hip_bfloat16* __restrict__ wk,
            float* __restrict__ out) {
    __shared__ short lds_x[2][6 * 64 * 32];   // 2 x 24KB; chunk idx <-> (cell, slot)

    const int tid   = threadIdx.x;
    const int lane  = tid & 63;
    const int g     = lane >> 4;
    const int l15   = lane & 15;
    const int w     = tid >> 6;
    const int wm    = w >> 1;
    const int wn    = w & 1;
    const int w64   = tid & ~63;

    const int flat  = blockIdx.x;
    const int swzid = (flat & 7) * 56 + (flat >> 3);
    const int b     = swzid / 28;
    const int rem   = swzid - b * 28;
    const int mtile = rem & 1;
    const int y0    = (rem >> 1) * 4;

    int cellb[7], cc[7], rr[7];
#pragma unroll
    for (int fn = 0; fn < 7; ++fn) {
        int n = wn * 112 + fn * 16 + l15;
        int r = n / 56, c = n % 56;
        rr[fn] = r; cc[fn] = c;
        cellb[fn] = r * 64 + c;
    }

    f32x4 acc[4][7];
#pragma unroll
    for (int fm = 0; fm < 4; ++fm)
#pragma unroll
        for (int fn = 0; fn < 7; ++fn) acc[fm][fn] = (f32x4){0.f, 0.f, 0.f, 0.f};

    const size_t xb = ((size_t)b * 58 + y0) * 64 * 256;
    // per-thread A base: frag-major wk + (b,kk=0,ci=0) + wave/lane offsets
    const char* wkb = (const char*)wk + (size_t)(b * 9) * 131072 +
                      (size_t)((mtile * 8 + wm * 4) * 1024 + l15 * 64 + g * 16);

#define STAGE_X(CI, BUF)                                                            \
    do {                                                                            \
        _Pragma("unroll")                                                           \
        for (int it = 0; it < 6; ++it) {                                            \
            int idx = it * 256 + tid;                                               \
            int sg  = idx & 3, cell = idx >> 2;                                     \
            int c = cell & 63;                                                      \
            int h = sg ^ ((c >> 1) & 3);                                            \
            const __hip_bfloat16* src = xpT + xb + (size_t)cell * 256 + (CI) * 32 + h * 8; \
            gl_lds16(src, (char*)lds_x[BUF] + (it * 256 + w64) * 16);               \
        }                                                                           \
    } while (0)

#define STEP(KK)                                                                    \
    do {                                                                            \
        bf16x8 af[4];                                                               \
        _Pragma("unroll")                                                           \
        for (int fm = 0; fm < 4; ++fm)                                              \
            af[fm] = *(const bf16x8*)(wkb + (size_t)((KK) * 131072 + ci * 16384 + fm * 1024)); \
        const int kh = (KK) / 3, kw = (KK) % 3;                                     \
        _Pragma("unroll")                                                           \
        for (int fn = 0; fn < 7; ++fn) {                                            \
            int cell = cellb[fn] + kh * 64 + kw;                                    \
            int slot = g ^ (((cc[fn] + kw) >> 1) & 3);                              \
            bf16x8 bfv = *(const bf16x8*)(xlds + cell * 64 + (slot << 4));          \
            _Pragma("unroll")                                                       \
            for (int fm = 0; fm < 4; ++fm)                                          \
                acc[fm][fn] = __builtin_amdgcn_mfma_f32_16x16x32_bf16(af[fm], bfv, acc[fm][fn], 0, 0, 0); \
        }                                                                           \
    } while (0)

    STAGE_X(0, 0);
    __syncthreads();

#pragma unroll 1
    for (int ci = 0; ci < 8; ++ci) {
        const char* xlds = (const char*)lds_x[ci & 1];
        if (ci < 7) STAGE_X(ci + 1, (ci & 1) ^ 1);   // in flight across the whole chunk
        STEP(0); STEP(1); STEP(2);
        STEP(3); STEP(4); STEP(5);
        STEP(6); STEP(7); STEP(8);
        if (ci < 7) __syncthreads();                  // single barrier per chunk
    }

    // epilogue: C/D layout col=l15, row=4*g+reg
    const int mbase = mtile * 128 + wm * 64;
#pragma unroll
    for (int fm = 0; fm < 4; ++fm)
#pragma unroll
        for (int fn = 0; fn < 7; ++fn) {
            int o = mbase + fm * 16 + 4 * g;
            float* op = out + (((size_t)b * 256 + o) * 56 + (y0 + rr[fn])) * 56 + cc[fn];
#pragma unroll
            for (int r = 0; r < 4; ++r) op[(size_t)r * HWHW] = acc[fm][fn][r];
        }
#undef STAGE_X
#undef STEP
}

extern "C" void kernel_launch(void* const* d_in, const int* in_sizes, int n_in,
                              void* d_out, int out_size, void* d_ws, size_t ws_size,
                              hipStream_t stream) {
    const float* x    = (const float*)d_in[0];
    const float* kern = (const float*)d_in[1];
    const float* w1   = (const float*)d_in[2];
    const float* b1   = (const float*)d_in[3];
    const float* w2   = (const float*)d_in[4];
    const float* b2   = (const float*)d_in[5];
    float* out = (float*)d_out;

    char* wsp = (char*)d_ws;
    __hip_bfloat16* xpT    = (__hip_bfloat16*)wsp;
    __hip_bfloat16* wkbuf  = (__hip_bfloat16*)(wsp + XPT_BYTES);
    float*          pooled = (float*)(wsp + XPT_BYTES + WK_BYTES);
    float*          alphas = (float*)(wsp + XPT_BYTES + WK_BYTES + POOL_BYTES);

    hipMemsetAsync(pooled, 0, POOL_BYTES, stream);

    xpose_pool_kernel<<<dim3(28, 16), dim3(256), 0, stream>>>(x, xpT, pooled);
    mlp_kernel<<<dim3(16), dim3(256), 0, stream>>>(pooled, w1, b1, w2, b2, alphas);
    wmix_kernel<<<dim3(256), dim3(256), 0, stream>>>(kern, alphas, wkbuf);
    conv_kernel<<<dim3(448), dim3(256), 0, stream>>>(xpT, wkbuf, out);
}

// Round 4
// 236.781 us; speedup vs baseline: 1.1902x; 1.0307x over previous
//
#include <hip/hip_runtime.h>
#include <hip/hip_bf16.h>
#include <stdint.h>

typedef __attribute__((ext_vector_type(8))) short bf16x8;
typedef __attribute__((ext_vector_type(4))) float f32x4;

#define BATCH 16
#define CH    256
#define HW    56
#define HWHW  3136   // 56*56
#define NK    8

// ---- workspace layout (bytes) ----
#define XPT_BYTES   30408704ul          // [16][58][64][256] bf16
#define WK_BYTES    18874368ul          // fragment-major: [b*9+kk][ci 8][frag 16][l15 16][g 4][e 8] bf16
#define POOL_BYTES  16384ul
#define ALPHA_BYTES 512ul

__device__ __forceinline__ void gl_lds16(const void* g, void* l) {
    __builtin_amdgcn_global_load_lds((const __attribute__((address_space(1))) uint32_t*)g,
                                     (__attribute__((address_space(3))) uint32_t*)l, 16, 0, 0);
}

__device__ __forceinline__ float bf16bits_to_f32(short h) {
    return __uint_as_float(((uint32_t)(uint16_t)h) << 16);
}

// ---------------- stage 1: fused transpose+pad+pool ----------------
__global__ void __launch_bounds__(256, 2)
xpose_pool_kernel(const float* __restrict__ x, __hip_bfloat16* __restrict__ xp,
                  float* __restrict__ pooled) {
    __shared__ short tile[2 * 56 * 256];   // [r][x][ch ^ ((x&7)<<3)]
    const int tid = threadIdx.x;
    const int ys  = blockIdx.x;            // 0..27
    const int b   = blockIdx.y;
    const int y0  = ys * 2;

    const float* xb = x + (size_t)b * CH * HWHW + (size_t)y0 * HW;
    for (int it = 0; it < 28; ++it) {
        int idx = it * 256 + tid;
        int ch  = idx / 28;
        int xi  = idx - ch * 28;
        int r   = xi / 14;
        int x4  = (xi - r * 14) * 4;
        const float4 v = *(const float4*)(xb + (size_t)ch * HWHW + r * HW + x4);
        const float* vf = (const float*)&v;
#pragma unroll
        for (int j = 0; j < 4; ++j) {
            __hip_bfloat16 h = __float2bfloat16(vf[j]);
            tile[(r * 56 + x4 + j) * 256 + (ch ^ (((x4 & 7) | j) << 3))] = *(const short*)&h;
        }
    }
    __syncthreads();

    {
        float s = 0.f;
        const int ch = tid;
        for (int r = 0; r < 2; ++r)
            for (int xx = 0; xx < 56; ++xx)
                s += bf16bits_to_f32(tile[(r * 56 + xx) * 256 + (ch ^ ((xx & 7) << 3))]);
        atomicAdd(&pooled[b * 256 + ch], s * (1.0f / 3136.0f));
    }

    __hip_bfloat16* dst0 = xp + ((size_t)(b * 58 + y0 + 1) * 64 + 1) * 256;
    for (int it = 0; it < 14; ++it) {
        int idx = it * 256 + tid;
        int ch0 = (idx & 31) * 8;
        int pos = idx >> 5;
        int r = pos / 56, xx = pos - (pos / 56) * 56;
        bf16x8 vv = *(const bf16x8*)&tile[(r * 56 + xx) * 256 + (ch0 ^ ((xx & 7) << 3))];
        *(bf16x8*)(dst0 + ((size_t)(r * 64 + xx)) * 256 + ch0) = vv;
    }

    bf16x8 z = {};
    if (tid < 128) {
        int r   = tid >> 6;
        int c2  = (tid >> 5) & 1;
        int ch0 = (tid & 31) * 8;
        *(bf16x8*)(xp + ((size_t)(b * 58 + y0 + 1 + r) * 64 + (c2 ? 57 : 0)) * 256 + ch0) = z;
    }
    if (ys == 0 || ys == 27) {
        int p = (ys == 0) ? 0 : 57;
        __hip_bfloat16* rowp = xp + (size_t)(b * 58 + p) * 64 * 256;
        for (int it = tid; it < 2048; it += 256)
            *(bf16x8*)(rowp + (size_t)it * 8) = z;
    }
}

// ---------------- stage 2: MLP + softmax, one block per batch sample ----------------
__global__ void __launch_bounds__(256)
mlp_kernel(const float* __restrict__ pooled,
           const float* __restrict__ w1, const float* __restrict__ b1,
           const float* __restrict__ w2, const float* __restrict__ b2,
           float* __restrict__ alphas) {
    const int b = blockIdx.x;
    __shared__ float pl[256];
    __shared__ float hp[4][64];
    __shared__ float h[64];
    __shared__ float sc[8];
    int t = threadIdx.x;
    pl[t] = pooled[b * 256 + t];
    __syncthreads();
    int j = t & 63, part = t >> 6;
    float s = 0.f;
    const float* w1p = w1 + part * 64 * 64 + j;
#pragma unroll 8
    for (int c = 0; c < 64; ++c) s += pl[part * 64 + c] * w1p[c * 64];
    hp[part][j] = s;
    __syncthreads();
    if (t < 64) h[t] = fmaxf(hp[0][t] + hp[1][t] + hp[2][t] + hp[3][t] + b1[t], 0.f);
    __syncthreads();
    if (t < 8) {
        float acc = b2[t];
#pragma unroll 8
        for (int jj = 0; jj < 64; ++jj) acc += h[jj] * w2[jj * 8 + t];
        sc[t] = acc;
    }
    __syncthreads();
    if (t == 0) {
        float m = sc[0];
#pragma unroll
        for (int k = 1; k < 8; ++k) m = fmaxf(m, sc[k]);
        float ssum = 0.f, e[8];
#pragma unroll
        for (int k = 0; k < 8; ++k) { e[k] = expf(sc[k] - m); ssum += e[k]; }
        float inv = 1.0f / ssum;
#pragma unroll
        for (int k = 0; k < 8; ++k) alphas[b * 8 + k] = e[k] * inv;
    }
}

// ---------------- stage 3: mix kernels -> fragment-major wk ----------------
__global__ void wmix_kernel(const float* __restrict__ kern, const float* __restrict__ alphas,
                            __hip_bfloat16* __restrict__ wk) {
    __shared__ float al[16][8];
    int t = threadIdx.x;
    if (t < 128) al[t >> 3][t & 7] = alphas[t];
    __syncthreads();
    const int o = blockIdx.x, i = t;
    const int idx = o * 256 + i;
    const size_t ibase = (size_t)((i >> 5) * 16384 + ((o >> 4)) * 1024 + (o & 15) * 64 +
                                  ((i >> 3) & 3) * 16 + (i & 7) * 2);
    float kv[8][9];
    const float* kp = kern + (size_t)idx * 9;
#pragma unroll
    for (int k = 0; k < 8; ++k)
#pragma unroll
        for (int q = 0; q < 9; ++q) kv[k][q] = kp[(size_t)k * 589824 + q];
    char* wkb = (char*)wk;
#pragma unroll 1
    for (int b = 0; b < 16; ++b) {
#pragma unroll
        for (int q = 0; q < 9; ++q) {
            float acc = 0.f;
#pragma unroll
            for (int k = 0; k < 8; ++k) acc += al[b][k] * kv[k][q];
            __hip_bfloat16 h = __float2bfloat16(acc);
            *(short*)(wkb + (size_t)(b * 9 + q) * 131072 + ibase) = *(const short*)&h;
        }
    }
}

// ---------------- stage 4: conv — register-pipelined, 8 barriers total ----------------
// flat grid 448 (XCD-chunked swizzle), block 256 (4 waves = 2M x 2N)
// BM=128, BN=224 = 4 out-rows x 56; K: 8 chunks of 32ch x 9 taps, chunk fully unrolled,
// A(global/L2) and B(LDS) double-buffered in registers with 1-step lookahead.
__global__ void __launch_bounds__(256, 1)
conv_kernel(const __hip_bfloat16* __restrict__ xpT, const __hip_bfloat16* __restrict__ wk,
            float* __restrict__ out) {
    __shared__ short lds_x[2][6 * 64 * 32];   // 2 x 24KB

    const int tid   = threadIdx.x;
    const int lane  = tid & 63;
    const int g     = lane >> 4;
    const int l15   = lane & 15;
    const int w     = tid >> 6;
    const int wm    = w >> 1;
    const int wn    = w & 1;
    const int w64   = tid & ~63;

    const int flat  = blockIdx.x;
    const int swzid = (flat & 7) * 56 + (flat >> 3);
    const int b     = swzid / 28;
    const int rem   = swzid - b * 28;
    const int mtile = rem & 1;
    const int y0    = (rem >> 1) * 4;

    int cellb[7], cc[7];
#pragma unroll
    for (int fn = 0; fn < 7; ++fn) {
        int n = wn * 112 + fn * 16 + l15;
        int r = n / 56, c = n % 56;
        cc[fn] = c;
        cellb[fn] = r * 64 + c;
    }

    f32x4 acc[4][7];
#pragma unroll
    for (int fm = 0; fm < 4; ++fm)
#pragma unroll
        for (int fn = 0; fn < 7; ++fn) acc[fm][fn] = (f32x4){0.f, 0.f, 0.f, 0.f};

    const size_t xb = ((size_t)b * 58 + y0) * 64 * 256;
    const char* wkb = (const char*)wk + (size_t)(b * 9) * 131072 +
                      (size_t)((mtile * 8 + wm * 4) * 1024 + l15 * 64 + g * 16);

#define STAGE_X(CI, BUF)                                                            \
    do {                                                                            \
        _Pragma("unroll")                                                           \
        for (int it = 0; it < 6; ++it) {                                            \
            int idx = it * 256 + tid;                                               \
            int sg  = idx & 3, cell = idx >> 2;                                     \
            int c = cell & 63;                                                      \
            int h = sg ^ ((c >> 1) & 3);                                            \
            const __hip_bfloat16* src = xpT + xb + (size_t)cell * 256 + (CI) * 32 + h * 8; \
            gl_lds16(src, (char*)lds_x[BUF] + (it * 256 + w64) * 16);               \
        }                                                                           \
    } while (0)

#define LOADA(KK, AR)                                                               \
    do {                                                                            \
        _Pragma("unroll")                                                           \
        for (int fm = 0; fm < 4; ++fm)                                              \
            AR[fm] = *(const bf16x8*)(wkb + (size_t)((KK) * 131072 + ci * 16384 + fm * 1024)); \
    } while (0)

#define LOADB(KK, BR)                                                               \
    do {                                                                            \
        const int kh = (KK) / 3, kw = (KK) % 3;                                     \
        _Pragma("unroll")                                                           \
        for (int fn = 0; fn < 7; ++fn) {                                            \
            int cell = cellb[fn] + kh * 64 + kw;                                    \
            int slot = g ^ (((cc[fn] + kw) >> 1) & 3);                              \
            BR[fn] = *(const bf16x8*)(xlds + cell * 64 + (slot << 4));              \
        }                                                                           \
    } while (0)

#define MM(AR, BR)                                                                  \
    do {                                                                            \
        __builtin_amdgcn_s_setprio(1);                                              \
        _Pragma("unroll")                                                           \
        for (int fn = 0; fn < 7; ++fn)                                              \
            _Pragma("unroll")                                                       \
            for (int fm = 0; fm < 4; ++fm)                                          \
                acc[fm][fn] = __builtin_amdgcn_mfma_f32_16x16x32_bf16(AR[fm], BR[fn], acc[fm][fn], 0, 0, 0); \
        __builtin_amdgcn_s_setprio(0);                                              \
    } while (0)

    STAGE_X(0, 0);
    __syncthreads();

#pragma unroll 1
    for (int ci = 0; ci < 8; ++ci) {
        const char* xlds = (const char*)lds_x[ci & 1];
        bf16x8 afA[4], afB[4], bfA[7], bfB[7];
        LOADA(0, afA); LOADB(0, bfA);
        if (ci < 7) STAGE_X(ci + 1, (ci & 1) ^ 1);   // async, overlaps whole chunk
        LOADA(1, afB); LOADB(1, bfB);
        MM(afA, bfA);
        LOADA(2, afA); LOADB(2, bfA); MM(afB, bfB);
        LOADA(3, afB); LOADB(3, bfB); MM(afA, bfA);
        LOADA(4, afA); LOADB(4, bfA); MM(afB, bfB);
        LOADA(5, afB); LOADB(5, bfB); MM(afA, bfA);
        LOADA(6, afA); LOADB(6, bfA); MM(afB, bfB);
        LOADA(7, afB); LOADB(7, bfB); MM(afA, bfA);
        LOADA(8, afA); LOADB(8, bfA); MM(afB, bfB);
        MM(afA, bfA);
        if (ci < 7) __syncthreads();                  // single barrier per chunk
    }

    // epilogue: C/D layout col=l15, row=4*g+reg
    const int mbase = mtile * 128 + wm * 64;
#pragma unroll
    for (int fm = 0; fm < 4; ++fm)
#pragma unroll
        for (int fn = 0; fn < 7; ++fn) {
            int n = wn * 112 + fn * 16 + l15;
            int r = n / 56, c = n - (n / 56) * 56;
            int o = mbase + fm * 16 + 4 * g;
            float* op = out + (((size_t)b * 256 + o) * 56 + (y0 + r)) * 56 + c;
#pragma unroll
            for (int q = 0; q < 4; ++q) op[(size_t)q * HWHW] = acc[fm][fn][q];
        }
#undef STAGE_X
#undef LOADA
#undef LOADB
#undef MM
}

extern "C" void kernel_launch(void* const* d_in, const int* in_sizes, int n_in,
                              void* d_out, int out_size, void* d_ws, size_t ws_size,
                              hipStream_t stream) {
    const float* x    = (const float*)d_in[0];
    const float* kern = (const float*)d_in[1];
    const float* w1   = (const float*)d_in[2];
    const float* b1   = (const float*)d_in[3];
    const float* w2   = (const float*)d_in[4];
    const float* b2   = (const float*)d_in[5];
    float* out = (float*)d_out;

    char* wsp = (char*)d_ws;
    __hip_bfloat16* xpT    = (__hip_bfloat16*)wsp;
    __hip_bfloat16* wkbuf  = (__hip_bfloat16*)(wsp + XPT_BYTES);
    float*          pooled = (float*)(wsp + XPT_BYTES + WK_BYTES);
    float*          alphas = (float*)(wsp + XPT_BYTES + WK_BYTES + POOL_BYTES);

    hipMemsetAsync(pooled, 0, POOL_BYTES, stream);

    xpose_pool_kernel<<<dim3(28, 16), dim3(256), 0, stream>>>(x, xpT, pooled);
    mlp_kernel<<<dim3(16), dim3(256), 0, stream>>>(pooled, w1, b1, w2, b2, alphas);
    wmix_kernel<<<dim3(256), dim3(256), 0, stream>>>(kern, alphas, wkbuf);
    conv_kernel<<<dim3(448), dim3(256), 0, stream>>>(xpT, wkbuf, out);
}